// Round 10
// baseline (234.550 us; speedup 1.0000x reference)
//
#include <hip/hip_runtime.h>
#include <math.h>

constexpr int NB = 2;      // batch
constexpr int SL = 2048;   // sequence length
constexpr int NV = 1024;   // model dim
constexpr int NH = 16;     // heads
constexpr int DH = 64;     // head dim
constexpr float LN_EPS = 1e-3f;

typedef __bf16 bf16_t;
typedef __bf16 v8bf __attribute__((ext_vector_type(8)));
typedef float  v4f  __attribute__((ext_vector_type(4)));

__device__ __forceinline__ v8bf cvt8(float4 a, float4 b) {
  v8bf v;
  v[0] = (bf16_t)a.x; v[1] = (bf16_t)a.y; v[2] = (bf16_t)a.z; v[3] = (bf16_t)a.w;
  v[4] = (bf16_t)b.x; v[5] = (bf16_t)b.y; v[6] = (bf16_t)b.z; v[7] = (bf16_t)b.w;
  return v;
}
__device__ __forceinline__ unsigned pack_bf16(float a, float b) {
  unsigned short ua = __builtin_bit_cast(unsigned short, (bf16_t)a);
  unsigned short ub = __builtin_bit_cast(unsigned short, (bf16_t)b);
  return (unsigned)ua | ((unsigned)ub << 16);
}
// async global->LDS, 16B/lane; LDS dest = wave-uniform base + lane*16.
__device__ __forceinline__ void async_cp16(const void* g, void* l) {
  __builtin_amdgcn_global_load_lds(
      (const __attribute__((address_space(1))) unsigned int*)g,
      (__attribute__((address_space(3))) unsigned int*)l, 16, 0, 0);
}

// ---------------------------------------------------------------------------
// W transpose+convert: W[h][v][d] fp32 -> Wt[z][n=h*64+d][v] bf16.
// Scale (1/8 * log2e) folded into Wq (softmax then uses exp2 directly).
__global__ __launch_bounds__(256)
void wcvt(const float* __restrict__ Wq, const float* __restrict__ Wk,
          const float* __restrict__ Wv, bf16_t* __restrict__ Wt) {
  __shared__ float ls[64][65];
  const int z = blockIdx.z;
  const float* W = z == 0 ? Wq : (z == 1 ? Wk : Wv);
  const float sc = z == 0 ? 0.125f * 1.44269504f : 1.0f;
  const int h = blockIdx.y, v0 = blockIdx.x * 64;
  const int t = threadIdx.x;
  const int rr = t >> 4, c4 = t & 15;
  const float* src = W + ((size_t)h * NV + v0) * DH;
#pragma unroll
  for (int it = 0; it < 4; ++it) {
    float4 f = *(const float4*)(src + (size_t)(rr + it * 16) * DH + c4 * 4);
    ls[rr + it * 16][c4 * 4 + 0] = f.x;
    ls[rr + it * 16][c4 * 4 + 1] = f.y;
    ls[rr + it * 16][c4 * 4 + 2] = f.z;
    ls[rr + it * 16][c4 * 4 + 3] = f.w;
  }
  __syncthreads();
  const int dd = t >> 2, vq = t & 3;
  bf16_t tmp[16];
#pragma unroll
  for (int i = 0; i < 16; ++i) tmp[i] = (bf16_t)(ls[vq * 16 + i][dd] * sc);
  bf16_t* dst = Wt + ((size_t)z * NV + h * 64 + dd) * NV + v0 + vq * 16;
  *(v8bf*)dst = *(v8bf*)&tmp[0];
  *(v8bf*)(dst + 8) = *(v8bf*)&tmp[8];
}

// ---------------------------------------------------------------------------
// Projection GEMM. Tile 64m x 128n, BK=32, double-buffered, ONE barrier/iter.
// 32KB LDS -> 5 blocks/CU resident (cross-block overlap hides barrier drain).
// A staged fp32 via coalesced global_load_lds (8 rows x 128B per instr),
// converted to bf16 at frag read; W staged bf16 via DMA.
// Grid 1536 (1D), id = z*512 + n*64 + m: the 8 n-blocks of one (z,m) A-slice
// share an XCD (id%8 == m%8).
// Q/K outputs [bh][l][d]; V output TRANSPOSED [bh][d][m], vm folded in.
__global__ __launch_bounds__(256, 5)
void proj_mfma(const float* __restrict__ A0, const float* __restrict__ A1,
               const float* __restrict__ A2, const bf16_t* __restrict__ Wtb,
               const int* __restrict__ vmask,
               bf16_t* __restrict__ O0, bf16_t* __restrict__ O1,
               bf16_t* __restrict__ O2) {
  __shared__ __align__(16) float  Asb[2][64 * 32];   // [m][k] 128B rows, XOR swz
  __shared__ __align__(16) bf16_t Wsb[2][128 * 32];  // [n][k] 64B rows, XOR swz

  const int id = blockIdx.x;
  const int z  = id >> 9;
  const int n0 = ((id >> 6) & 7) * 128;
  const int m0 = (id & 63) * 64;
  const float*  A   = z == 0 ? A0 : (z == 1 ? A1 : A2);
  bf16_t*       out = z == 0 ? O0 : (z == 1 ? O1 : O2);
  const bf16_t* W   = Wtb + (size_t)z * NV * NV;

  const int t = threadIdx.x, w = t >> 6, lane = t & 63;
  const int g = lane >> 4, lx = lane & 15;
  const int rbase = (w >> 1) * 32, cbase = (w & 1) * 64;

  auto stageA = [&](int k0, int buf) {
#pragma unroll
    for (int s = 0; s < 2; ++s) {
      const int r = w * 16 + s * 8 + (lane >> 3);
      const int c = (lane & 7) ^ (r & 7);
      async_cp16(A + (size_t)(m0 + r) * NV + k0 + c * 4,
                 (char*)Asb[buf] + (w * 16 + s * 8) * 128);
    }
  };
  auto stageW = [&](int k0, int buf) {
#pragma unroll
    for (int s = 0; s < 2; ++s) {
      const int r = w * 32 + s * 16 + (lane >> 2);
      const int c = (lane & 3) ^ (r & 3);
      async_cp16(W + (size_t)(n0 + r) * NV + k0 + c * 8,
                 (char*)Wsb[buf] + (w * 32 + s * 16) * 64);
    }
  };

  v4f acc[2][4] = {};

  stageA(0, 0);
  stageW(0, 0);
  __syncthreads();

  for (int it = 0; it < 32; ++it) {
    const int buf = it & 1;
    if (it < 31) { stageA((it + 1) * 32, buf ^ 1); stageW((it + 1) * 32, buf ^ 1); }
    v8bf af[2], wf[4];
#pragma unroll
    for (int rt = 0; rt < 2; ++rt) {
      const int row = rbase + rt * 16 + lx;
      const int sw = row & 7;
      float4 f0 = *(const float4*)((const char*)Asb[buf] + row * 128 + (((2 * g)     ^ sw) * 16));
      float4 f1 = *(const float4*)((const char*)Asb[buf] + row * 128 + (((2 * g + 1) ^ sw) * 16));
      af[rt] = cvt8(f0, f1);
    }
#pragma unroll
    for (int ct = 0; ct < 4; ++ct) {
      const int row = cbase + ct * 16 + lx;
      wf[ct] = *(const v8bf*)((const char*)Wsb[buf] + row * 64 +
                              ((g ^ (row & 3)) * 16));
    }
#pragma unroll
    for (int rt = 0; rt < 2; ++rt)
#pragma unroll
      for (int ct = 0; ct < 4; ++ct)
        acc[rt][ct] = __builtin_amdgcn_mfma_f32_16x16x32_bf16(
            af[rt], wf[ct], acc[rt][ct], 0, 0, 0);
    __syncthreads();  // drains next iter's async; orders this iter's reads
  }

  // epilogue. C-layout: row=(lane>>4)*4+reg, col=lane&15.
  if (z < 2) {  // Q/K: [bh][l][d]
#pragma unroll
    for (int rt = 0; rt < 2; ++rt) {
#pragma unroll
      for (int reg = 0; reg < 4; ++reg) {
        const int row = m0 + rbase + rt * 16 + g * 4 + reg;
        const int b = row >> 11, l = row & (SL - 1);
#pragma unroll
        for (int ct = 0; ct < 4; ++ct) {
          const int n = n0 + cbase + ct * 16 + lx;
          const int h = n >> 6, d = n & 63;
          out[((size_t)(b * NH + h) * SL + l) * DH + d] = (bf16_t)acc[rt][ct][reg];
        }
      }
    }
  } else {  // V: transposed [bh][d][m], vm folded in; b64 stores along m
#pragma unroll
    for (int rt = 0; rt < 2; ++rt) {
      const int row = m0 + rbase + rt * 16 + g * 4;  // regs = 4 consecutive m
      const int b = row >> 11, l = row & (SL - 1);
      float vm0 = (float)vmask[b * SL + l + 0];
      float vm1 = (float)vmask[b * SL + l + 1];
      float vm2 = (float)vmask[b * SL + l + 2];
      float vm3 = (float)vmask[b * SL + l + 3];
#pragma unroll
      for (int ct = 0; ct < 4; ++ct) {
        const int n = n0 + cbase + ct * 16 + lx;
        const int h = n >> 6, d = n & 63;
        uint2 u = {pack_bf16(acc[rt][ct][0] * vm0, acc[rt][ct][1] * vm1),
                   pack_bf16(acc[rt][ct][2] * vm2, acc[rt][ct][3] * vm3)};
        *(uint2*)&out[((size_t)(b * NH + h) * DH + d) * SL + l] = u;
      }
    }
  }
}

// ---------------------------------------------------------------------------
// Fused attention, q-tile 128, pure q-split (each wave: 32 q-rows x all m).
// Reference semantics: softmax denominator over ALL m (unmasked); PV masked
// by tril (vm folded into V^T); qm at epilogue. exp2, no max-tracking.
// K and V^T double-buffered in LDS via global_load_lds, one barrier per
// 64-m tile; P round-trip via wave-private LDS (no sync); wave-private
// epilogue (shfl only). XCD swizzle + heavy-first. Grid 512 (1D).
__global__ __launch_bounds__(256, 3)
void attn_mfma(const bf16_t* __restrict__ Qg, const bf16_t* __restrict__ Kg,
               const bf16_t* __restrict__ Vtg_all, const int* __restrict__ qmask,
               float* __restrict__ Xout) {
  __shared__ __align__(16) bf16_t kbuf[2][64 * 64];  // K[m][d], XOR swz
  __shared__ __align__(16) bf16_t vbuf[2][64 * 64];  // V^T[d][m], XOR swz
  __shared__ __align__(16) bf16_t Ps[4][32][72];     // per-wave P^T [q][m]

  const int id = blockIdx.x;
  const int bh = (id & 7) | ((id >> 7) << 3);  // same-XCD for fixed bh
  const int qb = 15 - ((id >> 3) & 15);        // heavy blocks first
  const int t = threadIdx.x, w = t >> 6, lane = t & 63;
  const int g = lane >> 4, lx = lane & 15;
  const int b = bh >> 4, h = bh & 15;
  const int l0 = qb * 128;
  const int lastAct = 2 * qb + 1;              // last m-tile with causal overlap

  const bf16_t* Kb  = Kg + (size_t)bh * SL * DH;
  const bf16_t* Vtg = Vtg_all + (size_t)bh * DH * SL;  // [d][m]

  // persistent Q B-frags: wave covers q in [l0 + w*32, +32)
  v8bf qf[2][2];
#pragma unroll
  for (int qt = 0; qt < 2; ++qt)
#pragma unroll
    for (int ks = 0; ks < 2; ++ks)
      qf[qt][ks] = *(const v8bf*)&Qg[((size_t)bh * SL + l0 + w * 32 + qt * 16 + lx) * DH +
                                     ks * 32 + g * 8];

  v4f O[2][4] = {};          // [qt][dt]
  float suml[2] = {0.f, 0.f};

  const int sr_off = lane >> 3, sc_l = lane & 7;
  auto stageK = [&](int mb, int buf) {
#pragma unroll
    for (int s = 0; s < 2; ++s) {
      const int r = w * 16 + s * 8 + sr_off;
      const int c = sc_l ^ (r & 7);
      async_cp16(Kb + (size_t)(mb + r) * DH + c * 8,
                 (char*)kbuf[buf] + (w * 16 + s * 8) * 128);
    }
  };
  auto stageV = [&](int mb, int buf) {
#pragma unroll
    for (int s = 0; s < 2; ++s) {
      const int r = w * 16 + s * 8 + sr_off;  // r = d row
      const int c = sc_l ^ (r & 7);
      async_cp16(Vtg + (size_t)r * SL + mb + c * 8,
                 (char*)vbuf[buf] + (w * 16 + s * 8) * 128);
    }
  };

  stageK(0, 0);
  stageV(0, 0);

  // ---- active tiles (causal overlap with [l0, l0+128)): S, P, PV ----
  for (int mt = 0; mt <= lastAct; ++mt) {
    const int pb = mt & 1;
    __syncthreads();  // drains async for tile mt; orders prev reads vs restage
    if (mt < SL / 64 - 1)  stageK((mt + 1) * 64, pb ^ 1);
    if (mt + 1 <= lastAct) stageV((mt + 1) * 64, pb ^ 1);

    // S^T: rows = m (mt2*16 + g*4 + reg), cols = q (lx)
    v4f S[4][2];  // [mt2][qt]
#pragma unroll
    for (int mt2 = 0; mt2 < 4; ++mt2) {
      S[mt2][0] = (v4f){0.f, 0.f, 0.f, 0.f};
      S[mt2][1] = (v4f){0.f, 0.f, 0.f, 0.f};
    }
#pragma unroll
    for (int ks = 0; ks < 2; ++ks)
#pragma unroll
      for (int mt2 = 0; mt2 < 4; ++mt2) {
        const int row = mt2 * 16 + lx;
        v8bf kf = *(const v8bf*)((const char*)kbuf[pb] + row * 128 +
                                 (((ks * 4 + g) ^ (lx & 7)) * 16));
#pragma unroll
        for (int qt = 0; qt < 2; ++qt)
          S[mt2][qt] = __builtin_amdgcn_mfma_f32_16x16x32_bf16(
              kf, qf[qt][ks], S[mt2][qt], 0, 0, 0);
      }

    const bool diagzone = (mt >= 2 * qb);  // only straddling tiles need masks
#pragma unroll
    for (int mt2 = 0; mt2 < 4; ++mt2)
#pragma unroll
      for (int qt = 0; qt < 2; ++qt) {
        float e0 = __builtin_amdgcn_exp2f(S[mt2][qt][0]);
        float e1 = __builtin_amdgcn_exp2f(S[mt2][qt][1]);
        float e2 = __builtin_amdgcn_exp2f(S[mt2][qt][2]);
        float e3 = __builtin_amdgcn_exp2f(S[mt2][qt][3]);
        suml[qt] += (e0 + e1) + (e2 + e3);  // denominator: unmasked
        if (diagzone) {
          const int ml = mt * 64 + mt2 * 16 + g * 4;
          const int ql = l0 + w * 32 + qt * 16 + lx;
          e0 = (ml + 0 <= ql) ? e0 : 0.f;
          e1 = (ml + 1 <= ql) ? e1 : 0.f;
          e2 = (ml + 2 <= ql) ? e2 : 0.f;
          e3 = (ml + 3 <= ql) ? e3 : 0.f;
        }
        uint2 u = {pack_bf16(e0, e1), pack_bf16(e2, e3)};
        *(uint2*)&Ps[w][qt * 16 + lx][mt2 * 16 + g * 4] = u;
      }

    // O += P . V   (Ps wave-private: same-wave LDS ordering suffices)
#pragma unroll
    for (int ks = 0; ks < 2; ++ks) {
      v8bf pf[2];
#pragma unroll
      for (int qt = 0; qt < 2; ++qt)
        pf[qt] = *(const v8bf*)&Ps[w][qt * 16 + lx][ks * 32 + g * 8];
#pragma unroll
      for (int dt = 0; dt < 4; ++dt) {
        const int row = dt * 16 + lx;
        v8bf vf = *(const v8bf*)((const char*)vbuf[pb] + row * 128 +
                                 (((ks * 4 + g) ^ (lx & 7)) * 16));
#pragma unroll
        for (int qt = 0; qt < 2; ++qt)
          O[qt][dt] = __builtin_amdgcn_mfma_f32_16x16x32_bf16(
              pf[qt], vf, O[qt][dt], 0, 0, 0);
      }
    }
  }

  // ---- future tiles: denominator only ----
  for (int mt = lastAct + 1; mt < SL / 64; ++mt) {
    const int pb = mt & 1;
    __syncthreads();
    if (mt < SL / 64 - 1) stageK((mt + 1) * 64, pb ^ 1);
    v4f S[4][2];
#pragma unroll
    for (int mt2 = 0; mt2 < 4; ++mt2) {
      S[mt2][0] = (v4f){0.f, 0.f, 0.f, 0.f};
      S[mt2][1] = (v4f){0.f, 0.f, 0.f, 0.f};
    }
#pragma unroll
    for (int ks = 0; ks < 2; ++ks)
#pragma unroll
      for (int mt2 = 0; mt2 < 4; ++mt2) {
        const int row = mt2 * 16 + lx;
        v8bf kf = *(const v8bf*)((const char*)kbuf[pb] + row * 128 +
                                 (((ks * 4 + g) ^ (lx & 7)) * 16));
#pragma unroll
        for (int qt = 0; qt < 2; ++qt)
          S[mt2][qt] = __builtin_amdgcn_mfma_f32_16x16x32_bf16(
              kf, qf[qt][ks], S[mt2][qt], 0, 0, 0);
      }
#pragma unroll
    for (int mt2 = 0; mt2 < 4; ++mt2)
#pragma unroll
      for (int qt = 0; qt < 2; ++qt)
        suml[qt] += (__builtin_amdgcn_exp2f(S[mt2][qt][0]) +
                     __builtin_amdgcn_exp2f(S[mt2][qt][1])) +
                    (__builtin_amdgcn_exp2f(S[mt2][qt][2]) +
                     __builtin_amdgcn_exp2f(S[mt2][qt][3]));
  }

  // ---- wave-private epilogue (no barrier, no cross-wave traffic) ----
  suml[0] += __shfl_xor(suml[0], 16); suml[0] += __shfl_xor(suml[0], 32);
  suml[1] += __shfl_xor(suml[1], 16); suml[1] += __shfl_xor(suml[1], 32);
#pragma unroll
  for (int qt = 0; qt < 2; ++qt) {
#pragma unroll
    for (int reg = 0; reg < 4; ++reg) {
      const int q = l0 + w * 32 + qt * 16 + g * 4 + reg;
      const float den = __shfl(suml[qt], g * 4 + reg);
      const float inv = (float)qmask[b * SL + q] / den;
#pragma unroll
      for (int dt = 0; dt < 4; ++dt)
        Xout[((size_t)(b * SL + q)) * NV + h * DH + dt * 16 + lx] =
            O[qt][dt][reg] * inv;
    }
  }
}

// ---------------------------------------------------------------------------
// Residual + LayerNorm over last dim (V=1024). 2 rows per block for ILP.
__global__ __launch_bounds__(256)
void ln_kernel(const float* __restrict__ X, const float* __restrict__ query,
               const float* __restrict__ gamma, const float* __restrict__ beta,
               float* __restrict__ out) {
  const int row0 = blockIdx.x * 2;
  const int t = threadIdx.x;
  float4 gv = *(const float4*)(gamma + t * 4);
  float4 bv = *(const float4*)(beta + t * 4);
  float y[2][4];
  float s[2], ss[2];
#pragma unroll
  for (int r = 0; r < 2; ++r) {
    float4 xv = *(const float4*)(X + (size_t)(row0 + r) * NV + t * 4);
    float4 qv = *(const float4*)(query + (size_t)(row0 + r) * NV + t * 4);
    y[r][0] = xv.x + qv.x; y[r][1] = xv.y + qv.y;
    y[r][2] = xv.z + qv.z; y[r][3] = xv.w + qv.w;
    s[r]  = (y[r][0] + y[r][1]) + (y[r][2] + y[r][3]);
    ss[r] = (y[r][0]*y[r][0] + y[r][1]*y[r][1]) + (y[r][2]*y[r][2] + y[r][3]*y[r][3]);
  }
#pragma unroll
  for (int off = 1; off < 64; off <<= 1) {
    s[0]  += __shfl_xor(s[0], off);  ss[0] += __shfl_xor(ss[0], off);
    s[1]  += __shfl_xor(s[1], off);  ss[1] += __shfl_xor(ss[1], off);
  }
  __shared__ float wsum[2][2][4];  // [r][{s,ss}][wave]
  const int wid = t >> 6;
  if ((t & 63) == 0) {
    wsum[0][0][wid] = s[0]; wsum[0][1][wid] = ss[0];
    wsum[1][0][wid] = s[1]; wsum[1][1][wid] = ss[1];
  }
  __syncthreads();
#pragma unroll
  for (int r = 0; r < 2; ++r) {
    float sr  = (wsum[r][0][0] + wsum[r][0][1]) + (wsum[r][0][2] + wsum[r][0][3]);
    float ssr = (wsum[r][1][0] + wsum[r][1][1]) + (wsum[r][1][2] + wsum[r][1][3]);
    const float mu   = sr * (1.f / NV);
    const float var  = ssr * (1.f / NV) - mu * mu;
    const float rstd = rsqrtf(var + LN_EPS);
    float4 o;
    o.x = gv.x * (y[r][0] - mu) * rstd + bv.x;
    o.y = gv.y * (y[r][1] - mu) * rstd + bv.y;
    o.z = gv.z * (y[r][2] - mu) * rstd + bv.z;
    o.w = gv.w * (y[r][3] - mu) * rstd + bv.w;
    *(float4*)(out + (size_t)(row0 + r) * NV + t * 4) = o;
  }
}

// ---------------------------------------------------------------------------
extern "C" void kernel_launch(void* const* d_in, const int* in_sizes, int n_in,
                              void* d_out, int out_size, void* d_ws, size_t ws_size,
                              hipStream_t stream) {
  const float* query = (const float*)d_in[0];
  const float* key_t = (const float*)d_in[1];
  const float* value = (const float*)d_in[2];
  const float* Wq    = (const float*)d_in[3];
  const float* Wk    = (const float*)d_in[4];
  const float* Wv    = (const float*)d_in[5];
  const float* gamma = (const float*)d_in[6];
  const float* beta  = (const float*)d_in[7];
  const int*   qmask = (const int*)d_in[8];
  const int*   vmask = (const int*)d_in[9];
  float* out = (float*)d_out;

  const size_t per = (size_t)NB * NH * SL * DH;  // 4,194,304 elements
  bf16_t* Qws = (bf16_t*)d_ws;
  bf16_t* Kws = Qws + per;
  bf16_t* Vws = Kws + per;   // transposed [bh][d][m], vm-masked
  bf16_t* Wtb = Vws + per;   // 3 * 1024*1024 bf16 = 6 MB

  wcvt<<<dim3(16, 16, 3), 256, 0, stream>>>(Wq, Wk, Wv, Wtb);
  proj_mfma<<<1536, 256, 0, stream>>>(query, key_t, value, Wtb,
                                      vmask, Qws, Kws, Vws);
  attn_mfma<<<512, 256, 0, stream>>>(Qws, Kws, Vws, qmask, out);
  ln_kernel<<<NB * SL / 2, 256, 0, stream>>>(out, query, gamma, beta, out);
}

// Round 11
// 230.847 us; speedup vs baseline: 1.0160x; 1.0160x over previous
//
#include <hip/hip_runtime.h>
#include <math.h>

constexpr int NB = 2;      // batch
constexpr int SL = 2048;   // sequence length
constexpr int NV = 1024;   // model dim
constexpr int NH = 16;     // heads
constexpr int DH = 64;     // head dim
constexpr float LN_EPS = 1e-3f;

typedef __bf16 bf16_t;
typedef __bf16 v8bf __attribute__((ext_vector_type(8)));
typedef float  v4f  __attribute__((ext_vector_type(4)));

__device__ __forceinline__ v8bf cvt8(float4 a, float4 b) {
  v8bf v;
  v[0] = (bf16_t)a.x; v[1] = (bf16_t)a.y; v[2] = (bf16_t)a.z; v[3] = (bf16_t)a.w;
  v[4] = (bf16_t)b.x; v[5] = (bf16_t)b.y; v[6] = (bf16_t)b.z; v[7] = (bf16_t)b.w;
  return v;
}
__device__ __forceinline__ unsigned pack_bf16(float a, float b) {
  unsigned short ua = __builtin_bit_cast(unsigned short, (bf16_t)a);
  unsigned short ub = __builtin_bit_cast(unsigned short, (bf16_t)b);
  return (unsigned)ua | ((unsigned)ub << 16);
}
// async global->LDS, 16B/lane; LDS dest = wave-uniform base + lane*16.
__device__ __forceinline__ void async_cp16(const void* g, void* l) {
  __builtin_amdgcn_global_load_lds(
      (const __attribute__((address_space(1))) unsigned int*)g,
      (__attribute__((address_space(3))) unsigned int*)l, 16, 0, 0);
}

// ---------------------------------------------------------------------------
// W transpose+convert: W[h][v][d] fp32 -> Wt[z][n=h*64+d][v] bf16.
// Scale (1/8 * log2e) folded into Wq (softmax then uses exp2 directly).
__global__ __launch_bounds__(256)
void wcvt(const float* __restrict__ Wq, const float* __restrict__ Wk,
          const float* __restrict__ Wv, bf16_t* __restrict__ Wt) {
  __shared__ float ls[64][65];
  const int z = blockIdx.z;
  const float* W = z == 0 ? Wq : (z == 1 ? Wk : Wv);
  const float sc = z == 0 ? 0.125f * 1.44269504f : 1.0f;
  const int h = blockIdx.y, v0 = blockIdx.x * 64;
  const int t = threadIdx.x;
  const int rr = t >> 4, c4 = t & 15;
  const float* src = W + ((size_t)h * NV + v0) * DH;
#pragma unroll
  for (int it = 0; it < 4; ++it) {
    float4 f = *(const float4*)(src + (size_t)(rr + it * 16) * DH + c4 * 4);
    ls[rr + it * 16][c4 * 4 + 0] = f.x;
    ls[rr + it * 16][c4 * 4 + 1] = f.y;
    ls[rr + it * 16][c4 * 4 + 2] = f.z;
    ls[rr + it * 16][c4 * 4 + 3] = f.w;
  }
  __syncthreads();
  const int dd = t >> 2, vq = t & 3;
  bf16_t tmp[16];
#pragma unroll
  for (int i = 0; i < 16; ++i) tmp[i] = (bf16_t)(ls[vq * 16 + i][dd] * sc);
  bf16_t* dst = Wt + ((size_t)z * NV + h * 64 + dd) * NV + v0 + vq * 16;
  *(v8bf*)dst = *(v8bf*)&tmp[0];
  *(v8bf*)(dst + 8) = *(v8bf*)&tmp[8];
}

// ---------------------------------------------------------------------------
// Projection GEMM (r6 structure + desync). BK=32, double-buffered, ONE
// barrier/iter, 48KB LDS, 3 blocks/CU. A staged fp32 via coalesced DMA,
// cvt to bf16 at frag read; W staged bf16 via DMA.
// Desync: (a) K-phase rotation — block m-index p starts at k-chunk p (sum is
// order-independent); same-m blocks (sharing A, same XCD) keep one phase.
// (b) s_sleep start stagger by m%3 breaks the barrier convoy across the ~3
// co-resident blocks per CU.
// Q/K outputs [bh][l][d]; V output TRANSPOSED [bh][d][m], vm folded in.
// Grid (32, 8, 3); 256 threads = 4 waves in 2x2, wave tile 64x64.
__global__ __launch_bounds__(256, 3)
void proj_mfma(const float* __restrict__ A0, const float* __restrict__ A1,
               const float* __restrict__ A2, const bf16_t* __restrict__ Wtb,
               const int* __restrict__ vmask,
               bf16_t* __restrict__ O0, bf16_t* __restrict__ O1,
               bf16_t* __restrict__ O2) {
  __shared__ __align__(16) float  Asb[2][128 * 32];   // [m][k] 128B rows, XOR swz
  __shared__ __align__(16) bf16_t Wsb[2][128 * 32];   // [n][k] 64B rows, XOR swz

  const int z = blockIdx.z;
  const float*  A   = z == 0 ? A0 : (z == 1 ? A1 : A2);
  bf16_t*       out = z == 0 ? O0 : (z == 1 ? O1 : O2);
  const bf16_t* W   = Wtb + (size_t)z * NV * NV;

  const int t = threadIdx.x, w = t >> 6, lane = t & 63;
  const int g = lane >> 4, lx = lane & 15;
  const int m0 = blockIdx.x * 128, n0 = blockIdx.y * 128;
  const int rbase = (w >> 1) * 64, cbase = (w & 1) * 64;

  // start stagger: ~1/3 and ~2/3 of the ~5K-cyc barrier period
  {
    const int ph = blockIdx.x % 3;
    if (ph == 1)      __builtin_amdgcn_s_sleep(26);
    else if (ph == 2) __builtin_amdgcn_s_sleep(52);
  }
  const int kph = blockIdx.x & 31;  // K-rotation phase (same for all n of a m)

  auto stageA = [&](int k0, int buf) {
#pragma unroll
    for (int s = 0; s < 4; ++s) {
      const int r = w * 32 + s * 8 + (lane >> 3);
      const int c = (lane & 7) ^ (r & 7);
      async_cp16(A + (size_t)(m0 + r) * NV + k0 + c * 4,
                 (char*)Asb[buf] + (w * 32 + s * 8) * 128);
    }
  };
  auto stageW = [&](int k0, int buf) {
#pragma unroll
    for (int s = 0; s < 2; ++s) {
      const int r = w * 32 + s * 16 + (lane >> 2);
      const int c = (lane & 3) ^ (r & 3);
      async_cp16(W + (size_t)(n0 + r) * NV + k0 + c * 8,
                 (char*)Wsb[buf] + (w * 32 + s * 16) * 64);
    }
  };
  auto kof = [&](int it) { return ((it + kph) & 31) * 32; };

  v4f acc[4][4] = {};
  stageA(kof(0), 0);
  stageW(kof(0), 0);

  for (int it = 0; it < 32; ++it) {
    const int buf = it & 1;
    __syncthreads();  // drains this iter's async; orders prev reads vs restage
    if (it < 31) { stageA(kof(it + 1), buf ^ 1); stageW(kof(it + 1), buf ^ 1); }
    v8bf af[4], wf[4];
#pragma unroll
    for (int rt = 0; rt < 4; ++rt) {
      const int row = rbase + rt * 16 + lx;
      const int sw = row & 7;
      float4 f0 = *(const float4*)((const char*)Asb[buf] + row * 128 + (((2 * g)     ^ sw) * 16));
      float4 f1 = *(const float4*)((const char*)Asb[buf] + row * 128 + (((2 * g + 1) ^ sw) * 16));
      af[rt] = cvt8(f0, f1);
    }
#pragma unroll
    for (int ct = 0; ct < 4; ++ct) {
      const int row = cbase + ct * 16 + lx;
      wf[ct] = *(const v8bf*)((const char*)Wsb[buf] + row * 64 +
                              ((g ^ (row & 3)) * 16));
    }
#pragma unroll
    for (int rt = 0; rt < 4; ++rt)
#pragma unroll
      for (int ct = 0; ct < 4; ++ct)
        acc[rt][ct] = __builtin_amdgcn_mfma_f32_16x16x32_bf16(
            af[rt], wf[ct], acc[rt][ct], 0, 0, 0);
  }

  // epilogue. C-layout: row=(lane>>4)*4+reg, col=lane&15.
  if (z < 2) {  // Q/K: [bh][l][d]
#pragma unroll
    for (int rt = 0; rt < 4; ++rt) {
#pragma unroll
      for (int reg = 0; reg < 4; ++reg) {
        const int row = m0 + rbase + rt * 16 + g * 4 + reg;
        const int b = row >> 11, l = row & (SL - 1);
#pragma unroll
        for (int ct = 0; ct < 4; ++ct) {
          const int n = n0 + cbase + ct * 16 + lx;
          const int h = n >> 6, d = n & 63;
          out[((size_t)(b * NH + h) * SL + l) * DH + d] = (bf16_t)acc[rt][ct][reg];
        }
      }
    }
  } else {  // V: transposed [bh][d][m], vm folded in; b64 stores along m
#pragma unroll
    for (int rt = 0; rt < 4; ++rt) {
      const int row = m0 + rbase + rt * 16 + g * 4;  // regs = 4 consecutive m
      const int b = row >> 11, l = row & (SL - 1);
      float vm0 = (float)vmask[b * SL + l + 0];
      float vm1 = (float)vmask[b * SL + l + 1];
      float vm2 = (float)vmask[b * SL + l + 2];
      float vm3 = (float)vmask[b * SL + l + 3];
#pragma unroll
      for (int ct = 0; ct < 4; ++ct) {
        const int n = n0 + cbase + ct * 16 + lx;
        const int h = n >> 6, d = n & 63;
        uint2 u = {pack_bf16(acc[rt][ct][0] * vm0, acc[rt][ct][1] * vm1),
                   pack_bf16(acc[rt][ct][2] * vm2, acc[rt][ct][3] * vm3)};
        *(uint2*)&out[((size_t)(b * NH + h) * DH + d) * SL + l] = u;
      }
    }
  }
}

// ---------------------------------------------------------------------------
// Fused attention (r9 structure + start stagger). q-tile 128, pure q-split
// (each wave: 32 q-rows x all m). Softmax denominator over ALL m (unmasked);
// PV masked by tril (vm folded into V^T); qm at epilogue. exp2, no
// max-tracking. K and V^T double-buffered via global_load_lds, one barrier
// per 64-m tile; P round-trip via wave-private LDS; wave-private epilogue.
// XCD swizzle + heavy-first. Same-XCD neighbor blocks staggered by s_sleep.
// Grid 512 (1D).
__global__ __launch_bounds__(256, 3)
void attn_mfma(const bf16_t* __restrict__ Qg, const bf16_t* __restrict__ Kg,
               const bf16_t* __restrict__ Vtg_all, const int* __restrict__ qmask,
               float* __restrict__ Xout) {
  __shared__ __align__(16) bf16_t kbuf[2][64 * 64];  // K[m][d], XOR swz
  __shared__ __align__(16) bf16_t vbuf[2][64 * 64];  // V^T[d][m], XOR swz
  __shared__ __align__(16) bf16_t Ps[4][32][72];     // per-wave P^T [q][m]

  const int id = blockIdx.x;
  const int bh = (id & 7) | ((id >> 7) << 3);  // same-XCD for fixed bh
  const int qb = 15 - ((id >> 3) & 15);        // heavy blocks first
  const int t = threadIdx.x, w = t >> 6, lane = t & 63;
  const int g = lane >> 4, lx = lane & 15;
  const int b = bh >> 4, h = bh & 15;
  const int l0 = qb * 128;
  const int lastAct = 2 * qb + 1;              // last m-tile with causal overlap

  if ((id >> 3) & 1) __builtin_amdgcn_s_sleep(32);  // desync same-XCD neighbors

  const bf16_t* Kb  = Kg + (size_t)bh * SL * DH;
  const bf16_t* Vtg = Vtg_all + (size_t)bh * DH * SL;  // [d][m]

  // persistent Q B-frags: wave covers q in [l0 + w*32, +32)
  v8bf qf[2][2];
#pragma unroll
  for (int qt = 0; qt < 2; ++qt)
#pragma unroll
    for (int ks = 0; ks < 2; ++ks)
      qf[qt][ks] = *(const v8bf*)&Qg[((size_t)bh * SL + l0 + w * 32 + qt * 16 + lx) * DH +
                                     ks * 32 + g * 8];

  v4f O[2][4] = {};          // [qt][dt]
  float suml[2] = {0.f, 0.f};

  const int sr_off = lane >> 3, sc_l = lane & 7;
  auto stageK = [&](int mb, int buf) {
#pragma unroll
    for (int s = 0; s < 2; ++s) {
      const int r = w * 16 + s * 8 + sr_off;
      const int c = sc_l ^ (r & 7);
      async_cp16(Kb + (size_t)(mb + r) * DH + c * 8,
                 (char*)kbuf[buf] + (w * 16 + s * 8) * 128);
    }
  };
  auto stageV = [&](int mb, int buf) {
#pragma unroll
    for (int s = 0; s < 2; ++s) {
      const int r = w * 16 + s * 8 + sr_off;  // r = d row
      const int c = sc_l ^ (r & 7);
      async_cp16(Vtg + (size_t)r * SL + mb + c * 8,
                 (char*)vbuf[buf] + (w * 16 + s * 8) * 128);
    }
  };

  stageK(0, 0);
  stageV(0, 0);

  // ---- active tiles (causal overlap with [l0, l0+128)): S, P, PV ----
  for (int mt = 0; mt <= lastAct; ++mt) {
    const int pb = mt & 1;
    __syncthreads();  // drains async for tile mt; orders prev reads vs restage
    if (mt < SL / 64 - 1)  stageK((mt + 1) * 64, pb ^ 1);
    if (mt + 1 <= lastAct) stageV((mt + 1) * 64, pb ^ 1);

    // S^T: rows = m (mt2*16 + g*4 + reg), cols = q (lx)
    v4f S[4][2];  // [mt2][qt]
#pragma unroll
    for (int mt2 = 0; mt2 < 4; ++mt2) {
      S[mt2][0] = (v4f){0.f, 0.f, 0.f, 0.f};
      S[mt2][1] = (v4f){0.f, 0.f, 0.f, 0.f};
    }
#pragma unroll
    for (int ks = 0; ks < 2; ++ks)
#pragma unroll
      for (int mt2 = 0; mt2 < 4; ++mt2) {
        const int row = mt2 * 16 + lx;
        v8bf kf = *(const v8bf*)((const char*)kbuf[pb] + row * 128 +
                                 (((ks * 4 + g) ^ (lx & 7)) * 16));
#pragma unroll
        for (int qt = 0; qt < 2; ++qt)
          S[mt2][qt] = __builtin_amdgcn_mfma_f32_16x16x32_bf16(
              kf, qf[qt][ks], S[mt2][qt], 0, 0, 0);
      }

    const bool diagzone = (mt >= 2 * qb);  // only straddling tiles need masks
#pragma unroll
    for (int mt2 = 0; mt2 < 4; ++mt2)
#pragma unroll
      for (int qt = 0; qt < 2; ++qt) {
        float e0 = __builtin_amdgcn_exp2f(S[mt2][qt][0]);
        float e1 = __builtin_amdgcn_exp2f(S[mt2][qt][1]);
        float e2 = __builtin_amdgcn_exp2f(S[mt2][qt][2]);
        float e3 = __builtin_amdgcn_exp2f(S[mt2][qt][3]);
        suml[qt] += (e0 + e1) + (e2 + e3);  // denominator: unmasked
        if (diagzone) {
          const int ml = mt * 64 + mt2 * 16 + g * 4;
          const int ql = l0 + w * 32 + qt * 16 + lx;
          e0 = (ml + 0 <= ql) ? e0 : 0.f;
          e1 = (ml + 1 <= ql) ? e1 : 0.f;
          e2 = (ml + 2 <= ql) ? e2 : 0.f;
          e3 = (ml + 3 <= ql) ? e3 : 0.f;
        }
        uint2 u = {pack_bf16(e0, e1), pack_bf16(e2, e3)};
        *(uint2*)&Ps[w][qt * 16 + lx][mt2 * 16 + g * 4] = u;
      }

    // O += P . V   (Ps wave-private: same-wave LDS ordering suffices)
#pragma unroll
    for (int ks = 0; ks < 2; ++ks) {
      v8bf pf[2];
#pragma unroll
      for (int qt = 0; qt < 2; ++qt)
        pf[qt] = *(const v8bf*)&Ps[w][qt * 16 + lx][ks * 32 + g * 8];
#pragma unroll
      for (int dt = 0; dt < 4; ++dt) {
        const int row = dt * 16 + lx;
        v8bf vf = *(const v8bf*)((const char*)vbuf[pb] + row * 128 +
                                 (((ks * 4 + g) ^ (lx & 7)) * 16));
#pragma unroll
        for (int qt = 0; qt < 2; ++qt)
          O[qt][dt] = __builtin_amdgcn_mfma_f32_16x16x32_bf16(
              pf[qt], vf, O[qt][dt], 0, 0, 0);
      }
    }
  }

  // ---- future tiles: denominator only ----
  for (int mt = lastAct + 1; mt < SL / 64; ++mt) {
    const int pb = mt & 1;
    __syncthreads();
    if (mt < SL / 64 - 1) stageK((mt + 1) * 64, pb ^ 1);
    v4f S[4][2];
#pragma unroll
    for (int mt2 = 0; mt2 < 4; ++mt2) {
      S[mt2][0] = (v4f){0.f, 0.f, 0.f, 0.f};
      S[mt2][1] = (v4f){0.f, 0.f, 0.f, 0.f};
    }
#pragma unroll
    for (int ks = 0; ks < 2; ++ks)
#pragma unroll
      for (int mt2 = 0; mt2 < 4; ++mt2) {
        const int row = mt2 * 16 + lx;
        v8bf kf = *(const v8bf*)((const char*)kbuf[pb] + row * 128 +
                                 (((ks * 4 + g) ^ (lx & 7)) * 16));
#pragma unroll
        for (int qt = 0; qt < 2; ++qt)
          S[mt2][qt] = __builtin_amdgcn_mfma_f32_16x16x32_bf16(
              kf, qf[qt][ks], S[mt2][qt], 0, 0, 0);
      }
#pragma unroll
    for (int mt2 = 0; mt2 < 4; ++mt2)
#pragma unroll
      for (int qt = 0; qt < 2; ++qt)
        suml[qt] += (__builtin_amdgcn_exp2f(S[mt2][qt][0]) +
                     __builtin_amdgcn_exp2f(S[mt2][qt][1])) +
                    (__builtin_amdgcn_exp2f(S[mt2][qt][2]) +
                     __builtin_amdgcn_exp2f(S[mt2][qt][3]));
  }

  // ---- wave-private epilogue (no barrier, no cross-wave traffic) ----
  suml[0] += __shfl_xor(suml[0], 16); suml[0] += __shfl_xor(suml[0], 32);
  suml[1] += __shfl_xor(suml[1], 16); suml[1] += __shfl_xor(suml[1], 32);
#pragma unroll
  for (int qt = 0; qt < 2; ++qt) {
#pragma unroll
    for (int reg = 0; reg < 4; ++reg) {
      const int q = l0 + w * 32 + qt * 16 + g * 4 + reg;
      const float den = __shfl(suml[qt], g * 4 + reg);
      const float inv = (float)qmask[b * SL + q] / den;
#pragma unroll
      for (int dt = 0; dt < 4; ++dt)
        Xout[((size_t)(b * SL + q)) * NV + h * DH + dt * 16 + lx] =
            O[qt][dt][reg] * inv;
    }
  }
}

// ---------------------------------------------------------------------------
// Residual + LayerNorm over last dim (V=1024). 2 rows per block for ILP.
__global__ __launch_bounds__(256)
void ln_kernel(const float* __restrict__ X, const float* __restrict__ query,
               const float* __restrict__ gamma, const float* __restrict__ beta,
               float* __restrict__ out) {
  const int row0 = blockIdx.x * 2;
  const int t = threadIdx.x;
  float4 gv = *(const float4*)(gamma + t * 4);
  float4 bv = *(const float4*)(beta + t * 4);
  float y[2][4];
  float s[2], ss[2];
#pragma unroll
  for (int r = 0; r < 2; ++r) {
    float4 xv = *(const float4*)(X + (size_t)(row0 + r) * NV + t * 4);
    float4 qv = *(const float4*)(query + (size_t)(row0 + r) * NV + t * 4);
    y[r][0] = xv.x + qv.x; y[r][1] = xv.y + qv.y;
    y[r][2] = xv.z + qv.z; y[r][3] = xv.w + qv.w;
    s[r]  = (y[r][0] + y[r][1]) + (y[r][2] + y[r][3]);
    ss[r] = (y[r][0]*y[r][0] + y[r][1]*y[r][1]) + (y[r][2]*y[r][2] + y[r][3]*y[r][3]);
  }
#pragma unroll
  for (int off = 1; off < 64; off <<= 1) {
    s[0]  += __shfl_xor(s[0], off);  ss[0] += __shfl_xor(ss[0], off);
    s[1]  += __shfl_xor(s[1], off);  ss[1] += __shfl_xor(ss[1], off);
  }
  __shared__ float wsum[2][2][4];  // [r][{s,ss}][wave]
  const int wid = t >> 6;
  if ((t & 63) == 0) {
    wsum[0][0][wid] = s[0]; wsum[0][1][wid] = ss[0];
    wsum[1][0][wid] = s[1]; wsum[1][1][wid] = ss[1];
  }
  __syncthreads();
#pragma unroll
  for (int r = 0; r < 2; ++r) {
    float sr  = (wsum[r][0][0] + wsum[r][0][1]) + (wsum[r][0][2] + wsum[r][0][3]);
    float ssr = (wsum[r][1][0] + wsum[r][1][1]) + (wsum[r][1][2] + wsum[r][1][3]);
    const float mu   = sr * (1.f / NV);
    const float var  = ssr * (1.f / NV) - mu * mu;
    const float rstd = rsqrtf(var + LN_EPS);
    float4 o;
    o.x = gv.x * (y[r][0] - mu) * rstd + bv.x;
    o.y = gv.y * (y[r][1] - mu) * rstd + bv.y;
    o.z = gv.z * (y[r][2] - mu) * rstd + bv.z;
    o.w = gv.w * (y[r][3] - mu) * rstd + bv.w;
    *(float4*)(out + (size_t)(row0 + r) * NV + t * 4) = o;
  }
}

// ---------------------------------------------------------------------------
extern "C" void kernel_launch(void* const* d_in, const int* in_sizes, int n_in,
                              void* d_out, int out_size, void* d_ws, size_t ws_size,
                              hipStream_t stream) {
  const float* query = (const float*)d_in[0];
  const float* key_t = (const float*)d_in[1];
  const float* value = (const float*)d_in[2];
  const float* Wq    = (const float*)d_in[3];
  const float* Wk    = (const float*)d_in[4];
  const float* Wv    = (const float*)d_in[5];
  const float* gamma = (const float*)d_in[6];
  const float* beta  = (const float*)d_in[7];
  const int*   qmask = (const int*)d_in[8];
  const int*   vmask = (const int*)d_in[9];
  float* out = (float*)d_out;

  const size_t per = (size_t)NB * NH * SL * DH;  // 4,194,304 elements
  bf16_t* Qws = (bf16_t*)d_ws;
  bf16_t* Kws = Qws + per;
  bf16_t* Vws = Kws + per;   // transposed [bh][d][m], vm-masked
  bf16_t* Wtb = Vws + per;   // 3 * 1024*1024 bf16 = 6 MB

  wcvt<<<dim3(16, 16, 3), 256, 0, stream>>>(Wq, Wk, Wv, Wtb);
  proj_mfma<<<dim3(32, 8, 3), 256, 0, stream>>>(query, key_t, value, Wtb,
                                                vmask, Qws, Kws, Vws);
  attn_mfma<<<512, 256, 0, stream>>>(Qws, Kws, Vws, qmask, out);
  ln_kernel<<<NB * SL / 2, 256, 0, stream>>>(out, query, gamma, beta, out);
}

// Round 12
// 209.453 us; speedup vs baseline: 1.1198x; 1.1021x over previous
//
#include <hip/hip_runtime.h>
#include <math.h>

constexpr int NB = 2;      // batch
constexpr int SL = 2048;   // sequence length
constexpr int NV = 1024;   // model dim
constexpr int NH = 16;     // heads
constexpr int DH = 64;     // head dim
constexpr float LN_EPS = 1e-3f;

typedef __bf16 bf16_t;
typedef __bf16 v8bf __attribute__((ext_vector_type(8)));
typedef float  v4f  __attribute__((ext_vector_type(4)));

__device__ __forceinline__ unsigned pack_bf16(float a, float b) {
  unsigned short ua = __builtin_bit_cast(unsigned short, (bf16_t)a);
  unsigned short ub = __builtin_bit_cast(unsigned short, (bf16_t)b);
  return (unsigned)ua | ((unsigned)ub << 16);
}
// async global->LDS, 16B/lane; LDS dest = wave-uniform base + lane*16.
__device__ __forceinline__ void async_cp16(const void* g, void* l) {
  __builtin_amdgcn_global_load_lds(
      (const __attribute__((address_space(1))) unsigned int*)g,
      (__attribute__((address_space(3))) unsigned int*)l, 16, 0, 0);
}

// ---------------------------------------------------------------------------
// A cast: fp32 -> bf16, fully coalesced (one float4 -> uint2 per thread).
__global__ __launch_bounds__(256)
void acvt(const float* __restrict__ q, const float* __restrict__ k,
          const float* __restrict__ v, bf16_t* __restrict__ oq,
          bf16_t* __restrict__ ok, bf16_t* __restrict__ ov) {
  const int z = blockIdx.y;
  const float* src = z == 0 ? q : (z == 1 ? k : v);
  bf16_t*      dst = z == 0 ? oq : (z == 1 ? ok : ov);
  const size_t i = ((size_t)blockIdx.x * 256 + threadIdx.x) * 4;
  float4 f = *(const float4*)(src + i);
  uint2 u = {pack_bf16(f.x, f.y), pack_bf16(f.z, f.w)};
  *(uint2*)(dst + i) = u;
}

// ---------------------------------------------------------------------------
// W transpose+convert: W[h][v][d] fp32 -> Wt[z][n=h*64+d][v] bf16.
// Scale (1/8 * log2e) folded into Wq (softmax then uses exp2 directly).
__global__ __launch_bounds__(256)
void wcvt(const float* __restrict__ Wq, const float* __restrict__ Wk,
          const float* __restrict__ Wv, bf16_t* __restrict__ Wt) {
  __shared__ float ls[64][65];
  const int z = blockIdx.z;
  const float* W = z == 0 ? Wq : (z == 1 ? Wk : Wv);
  const float sc = z == 0 ? 0.125f * 1.44269504f : 1.0f;
  const int h = blockIdx.y, v0 = blockIdx.x * 64;
  const int t = threadIdx.x;
  const int rr = t >> 4, c4 = t & 15;
  const float* src = W + ((size_t)h * NV + v0) * DH;
#pragma unroll
  for (int it = 0; it < 4; ++it) {
    float4 f = *(const float4*)(src + (size_t)(rr + it * 16) * DH + c4 * 4);
    ls[rr + it * 16][c4 * 4 + 0] = f.x;
    ls[rr + it * 16][c4 * 4 + 1] = f.y;
    ls[rr + it * 16][c4 * 4 + 2] = f.z;
    ls[rr + it * 16][c4 * 4 + 3] = f.w;
  }
  __syncthreads();
  const int dd = t >> 2, vq = t & 3;
  bf16_t tmp[16];
#pragma unroll
  for (int i = 0; i < 16; ++i) tmp[i] = (bf16_t)(ls[vq * 16 + i][dd] * sc);
  bf16_t* dst = Wt + ((size_t)z * NV + h * 64 + dd) * NV + v0 + vq * 16;
  *(v8bf*)dst = *(v8bf*)&tmp[0];
  *(v8bf*)(dst + 8) = *(v8bf*)&tmp[8];
}

// ---------------------------------------------------------------------------
// Projection GEMM, ALL-bf16 (A pre-cast by acvt). BK=32, double-buffered,
// ONE barrier/iter, 32KB LDS. Both operands DMA-staged as 64B rows (16 rows
// per async_cp16, fully coalesced), 4-chunk XOR swizzle. Per wave per iter:
// 8 ds_read_b128 + 16 MFMA (no cvt VALU) — roughly half r6/r11's per-iter
// critical path. Grid (32,8,3): same-m blocks share an XCD (id%8 == m%8) so
// the A-slice and W stream stay L2-resident.
// Q/K outputs [bh][l][d]; V output TRANSPOSED [bh][d][m], vm folded in.
__global__ __launch_bounds__(256, 4)
void proj_mfma(const bf16_t* __restrict__ A0, const bf16_t* __restrict__ A1,
               const bf16_t* __restrict__ A2, const bf16_t* __restrict__ Wtb,
               const int* __restrict__ vmask,
               bf16_t* __restrict__ O0, bf16_t* __restrict__ O1,
               bf16_t* __restrict__ O2) {
  __shared__ __align__(16) bf16_t Asb[2][128 * 32];  // [m][k] 64B rows, XOR swz
  __shared__ __align__(16) bf16_t Wsb[2][128 * 32];  // [n][k] 64B rows, XOR swz

  const int z = blockIdx.z;
  const bf16_t* A   = z == 0 ? A0 : (z == 1 ? A1 : A2);
  bf16_t*       out = z == 0 ? O0 : (z == 1 ? O1 : O2);
  const bf16_t* W   = Wtb + (size_t)z * NV * NV;

  const int t = threadIdx.x, w = t >> 6, lane = t & 63;
  const int g = lane >> 4, lx = lane & 15;
  const int m0 = blockIdx.x * 128, n0 = blockIdx.y * 128;
  const int rbase = (w >> 1) * 64, cbase = (w & 1) * 64;

  const int sr = lane >> 2;           // 16 rows per instr, 4 lanes/row
  const int sc = (lane & 3);
  auto stageA = [&](int k0, int buf) {
#pragma unroll
    for (int s = 0; s < 2; ++s) {
      const int r = w * 32 + s * 16 + sr;
      const int c = sc ^ (r & 3);
      async_cp16(A + (size_t)(m0 + r) * NV + k0 + c * 8,
                 (char*)Asb[buf] + (w * 32 + s * 16) * 64);
    }
  };
  auto stageW = [&](int k0, int buf) {
#pragma unroll
    for (int s = 0; s < 2; ++s) {
      const int r = w * 32 + s * 16 + sr;
      const int c = sc ^ (r & 3);
      async_cp16(W + (size_t)(n0 + r) * NV + k0 + c * 8,
                 (char*)Wsb[buf] + (w * 32 + s * 16) * 64);
    }
  };

  v4f acc[4][4] = {};
  stageA(0, 0);
  stageW(0, 0);

  for (int it = 0; it < 32; ++it) {
    const int buf = it & 1;
    __syncthreads();  // drains this iter's async; orders prev reads vs restage
    if (it < 31) {
      stageA((it + 1) * 32, buf ^ 1);
      stageW((it + 1) * 32, buf ^ 1);
    }
    v8bf af[4], wf[4];
#pragma unroll
    for (int rt = 0; rt < 4; ++rt) {
      const int row = rbase + rt * 16 + lx;
      af[rt] = *(const v8bf*)((const char*)Asb[buf] + row * 64 +
                              ((g ^ (row & 3)) * 16));
    }
#pragma unroll
    for (int ct = 0; ct < 4; ++ct) {
      const int row = cbase + ct * 16 + lx;
      wf[ct] = *(const v8bf*)((const char*)Wsb[buf] + row * 64 +
                              ((g ^ (row & 3)) * 16));
    }
#pragma unroll
    for (int rt = 0; rt < 4; ++rt)
#pragma unroll
      for (int ct = 0; ct < 4; ++ct)
        acc[rt][ct] = __builtin_amdgcn_mfma_f32_16x16x32_bf16(
            af[rt], wf[ct], acc[rt][ct], 0, 0, 0);
  }

  // epilogue. C-layout: row=(lane>>4)*4+reg, col=lane&15.
  if (z < 2) {  // Q/K: [bh][l][d]
#pragma unroll
    for (int rt = 0; rt < 4; ++rt) {
#pragma unroll
      for (int reg = 0; reg < 4; ++reg) {
        const int row = m0 + rbase + rt * 16 + g * 4 + reg;
        const int b = row >> 11, l = row & (SL - 1);
#pragma unroll
        for (int ct = 0; ct < 4; ++ct) {
          const int n = n0 + cbase + ct * 16 + lx;
          const int h = n >> 6, d = n & 63;
          out[((size_t)(b * NH + h) * SL + l) * DH + d] = (bf16_t)acc[rt][ct][reg];
        }
      }
    }
  } else {  // V: transposed [bh][d][m], vm folded in; b64 stores along m
#pragma unroll
    for (int rt = 0; rt < 4; ++rt) {
      const int row = m0 + rbase + rt * 16 + g * 4;  // regs = 4 consecutive m
      const int b = row >> 11, l = row & (SL - 1);
      float vm0 = (float)vmask[b * SL + l + 0];
      float vm1 = (float)vmask[b * SL + l + 1];
      float vm2 = (float)vmask[b * SL + l + 2];
      float vm3 = (float)vmask[b * SL + l + 3];
#pragma unroll
      for (int ct = 0; ct < 4; ++ct) {
        const int n = n0 + cbase + ct * 16 + lx;
        const int h = n >> 6, d = n & 63;
        uint2 u = {pack_bf16(acc[rt][ct][0] * vm0, acc[rt][ct][1] * vm1),
                   pack_bf16(acc[rt][ct][2] * vm2, acc[rt][ct][3] * vm3)};
        *(uint2*)&out[((size_t)(b * NH + h) * DH + d) * SL + l] = u;
      }
    }
  }
}

// ---------------------------------------------------------------------------
// Fused attention (r9 structure). q-tile 128, pure q-split (each wave: 32
// q-rows x all m). Softmax denominator over ALL m (unmasked); PV masked by
// tril (vm folded into V^T); qm at epilogue. exp2, no max-tracking. K and
// V^T double-buffered via global_load_lds, one barrier per 64-m tile; P
// round-trip via wave-private LDS; wave-private epilogue. XCD swizzle +
// heavy-first. Grid 512 (1D).
__global__ __launch_bounds__(256, 3)
void attn_mfma(const bf16_t* __restrict__ Qg, const bf16_t* __restrict__ Kg,
               const bf16_t* __restrict__ Vtg_all, const int* __restrict__ qmask,
               float* __restrict__ Xout) {
  __shared__ __align__(16) bf16_t kbuf[2][64 * 64];  // K[m][d], XOR swz
  __shared__ __align__(16) bf16_t vbuf[2][64 * 64];  // V^T[d][m], XOR swz
  __shared__ __align__(16) bf16_t Ps[4][32][72];     // per-wave P^T [q][m]

  const int id = blockIdx.x;
  const int bh = (id & 7) | ((id >> 7) << 3);  // same-XCD for fixed bh
  const int qb = 15 - ((id >> 3) & 15);        // heavy blocks first
  const int t = threadIdx.x, w = t >> 6, lane = t & 63;
  const int g = lane >> 4, lx = lane & 15;
  const int b = bh >> 4, h = bh & 15;
  const int l0 = qb * 128;
  const int lastAct = 2 * qb + 1;              // last m-tile with causal overlap

  const bf16_t* Kb  = Kg + (size_t)bh * SL * DH;
  const bf16_t* Vtg = Vtg_all + (size_t)bh * DH * SL;  // [d][m]

  // persistent Q B-frags: wave covers q in [l0 + w*32, +32)
  v8bf qf[2][2];
#pragma unroll
  for (int qt = 0; qt < 2; ++qt)
#pragma unroll
    for (int ks = 0; ks < 2; ++ks)
      qf[qt][ks] = *(const v8bf*)&Qg[((size_t)bh * SL + l0 + w * 32 + qt * 16 + lx) * DH +
                                     ks * 32 + g * 8];

  v4f O[2][4] = {};          // [qt][dt]
  float suml[2] = {0.f, 0.f};

  const int sr_off = lane >> 3, sc_l = lane & 7;
  auto stageK = [&](int mb, int buf) {
#pragma unroll
    for (int s = 0; s < 2; ++s) {
      const int r = w * 16 + s * 8 + sr_off;
      const int c = sc_l ^ (r & 7);
      async_cp16(Kb + (size_t)(mb + r) * DH + c * 8,
                 (char*)kbuf[buf] + (w * 16 + s * 8) * 128);
    }
  };
  auto stageV = [&](int mb, int buf) {
#pragma unroll
    for (int s = 0; s < 2; ++s) {
      const int r = w * 16 + s * 8 + sr_off;  // r = d row
      const int c = sc_l ^ (r & 7);
      async_cp16(Vtg + (size_t)r * SL + mb + c * 8,
                 (char*)vbuf[buf] + (w * 16 + s * 8) * 128);
    }
  };

  stageK(0, 0);
  stageV(0, 0);

  // ---- active tiles (causal overlap with [l0, l0+128)): S, P, PV ----
  for (int mt = 0; mt <= lastAct; ++mt) {
    const int pb = mt & 1;
    __syncthreads();  // drains async for tile mt; orders prev reads vs restage
    if (mt < SL / 64 - 1)  stageK((mt + 1) * 64, pb ^ 1);
    if (mt + 1 <= lastAct) stageV((mt + 1) * 64, pb ^ 1);

    // S^T: rows = m (mt2*16 + g*4 + reg), cols = q (lx)
    v4f S[4][2];  // [mt2][qt]
#pragma unroll
    for (int mt2 = 0; mt2 < 4; ++mt2) {
      S[mt2][0] = (v4f){0.f, 0.f, 0.f, 0.f};
      S[mt2][1] = (v4f){0.f, 0.f, 0.f, 0.f};
    }
#pragma unroll
    for (int ks = 0; ks < 2; ++ks)
#pragma unroll
      for (int mt2 = 0; mt2 < 4; ++mt2) {
        const int row = mt2 * 16 + lx;
        v8bf kf = *(const v8bf*)((const char*)kbuf[pb] + row * 128 +
                                 (((ks * 4 + g) ^ (lx & 7)) * 16));
#pragma unroll
        for (int qt = 0; qt < 2; ++qt)
          S[mt2][qt] = __builtin_amdgcn_mfma_f32_16x16x32_bf16(
              kf, qf[qt][ks], S[mt2][qt], 0, 0, 0);
      }

    const bool diagzone = (mt >= 2 * qb);  // only straddling tiles need masks
#pragma unroll
    for (int mt2 = 0; mt2 < 4; ++mt2)
#pragma unroll
      for (int qt = 0; qt < 2; ++qt) {
        float e0 = __builtin_amdgcn_exp2f(S[mt2][qt][0]);
        float e1 = __builtin_amdgcn_exp2f(S[mt2][qt][1]);
        float e2 = __builtin_amdgcn_exp2f(S[mt2][qt][2]);
        float e3 = __builtin_amdgcn_exp2f(S[mt2][qt][3]);
        suml[qt] += (e0 + e1) + (e2 + e3);  // denominator: unmasked
        if (diagzone) {
          const int ml = mt * 64 + mt2 * 16 + g * 4;
          const int ql = l0 + w * 32 + qt * 16 + lx;
          e0 = (ml + 0 <= ql) ? e0 : 0.f;
          e1 = (ml + 1 <= ql) ? e1 : 0.f;
          e2 = (ml + 2 <= ql) ? e2 : 0.f;
          e3 = (ml + 3 <= ql) ? e3 : 0.f;
        }
        uint2 u = {pack_bf16(e0, e1), pack_bf16(e2, e3)};
        *(uint2*)&Ps[w][qt * 16 + lx][mt2 * 16 + g * 4] = u;
      }

    // O += P . V   (Ps wave-private: same-wave LDS ordering suffices)
#pragma unroll
    for (int ks = 0; ks < 2; ++ks) {
      v8bf pf[2];
#pragma unroll
      for (int qt = 0; qt < 2; ++qt)
        pf[qt] = *(const v8bf*)&Ps[w][qt * 16 + lx][ks * 32 + g * 8];
#pragma unroll
      for (int dt = 0; dt < 4; ++dt) {
        const int row = dt * 16 + lx;
        v8bf vf = *(const v8bf*)((const char*)vbuf[pb] + row * 128 +
                                 (((ks * 4 + g) ^ (lx & 7)) * 16));
#pragma unroll
        for (int qt = 0; qt < 2; ++qt)
          O[qt][dt] = __builtin_amdgcn_mfma_f32_16x16x32_bf16(
              pf[qt], vf, O[qt][dt], 0, 0, 0);
      }
    }
  }

  // ---- future tiles: denominator only ----
  for (int mt = lastAct + 1; mt < SL / 64; ++mt) {
    const int pb = mt & 1;
    __syncthreads();
    if (mt < SL / 64 - 1) stageK((mt + 1) * 64, pb ^ 1);
    v4f S[4][2];
#pragma unroll
    for (int mt2 = 0; mt2 < 4; ++mt2) {
      S[mt2][0] = (v4f){0.f, 0.f, 0.f, 0.f};
      S[mt2][1] = (v4f){0.f, 0.f, 0.f, 0.f};
    }
#pragma unroll
    for (int ks = 0; ks < 2; ++ks)
#pragma unroll
      for (int mt2 = 0; mt2 < 4; ++mt2) {
        const int row = mt2 * 16 + lx;
        v8bf kf = *(const v8bf*)((const char*)kbuf[pb] + row * 128 +
                                 (((ks * 4 + g) ^ (lx & 7)) * 16));
#pragma unroll
        for (int qt = 0; qt < 2; ++qt)
          S[mt2][qt] = __builtin_amdgcn_mfma_f32_16x16x32_bf16(
              kf, qf[qt][ks], S[mt2][qt], 0, 0, 0);
      }
#pragma unroll
    for (int mt2 = 0; mt2 < 4; ++mt2)
#pragma unroll
      for (int qt = 0; qt < 2; ++qt)
        suml[qt] += (__builtin_amdgcn_exp2f(S[mt2][qt][0]) +
                     __builtin_amdgcn_exp2f(S[mt2][qt][1])) +
                    (__builtin_amdgcn_exp2f(S[mt2][qt][2]) +
                     __builtin_amdgcn_exp2f(S[mt2][qt][3]));
  }

  // ---- wave-private epilogue (no barrier, no cross-wave traffic) ----
  suml[0] += __shfl_xor(suml[0], 16); suml[0] += __shfl_xor(suml[0], 32);
  suml[1] += __shfl_xor(suml[1], 16); suml[1] += __shfl_xor(suml[1], 32);
#pragma unroll
  for (int qt = 0; qt < 2; ++qt) {
#pragma unroll
    for (int reg = 0; reg < 4; ++reg) {
      const int q = l0 + w * 32 + qt * 16 + g * 4 + reg;
      const float den = __shfl(suml[qt], g * 4 + reg);
      const float inv = (float)qmask[b * SL + q] / den;
#pragma unroll
      for (int dt = 0; dt < 4; ++dt)
        Xout[((size_t)(b * SL + q)) * NV + h * DH + dt * 16 + lx] =
            O[qt][dt][reg] * inv;
    }
  }
}

// ---------------------------------------------------------------------------
// Residual + LayerNorm over last dim (V=1024). 2 rows per block for ILP.
__global__ __launch_bounds__(256)
void ln_kernel(const float* __restrict__ X, const float* __restrict__ query,
               const float* __restrict__ gamma, const float* __restrict__ beta,
               float* __restrict__ out) {
  const int row0 = blockIdx.x * 2;
  const int t = threadIdx.x;
  float4 gv = *(const float4*)(gamma + t * 4);
  float4 bv = *(const float4*)(beta + t * 4);
  float y[2][4];
  float s[2], ss[2];
#pragma unroll
  for (int r = 0; r < 2; ++r) {
    float4 xv = *(const float4*)(X + (size_t)(row0 + r) * NV + t * 4);
    float4 qv = *(const float4*)(query + (size_t)(row0 + r) * NV + t * 4);
    y[r][0] = xv.x + qv.x; y[r][1] = xv.y + qv.y;
    y[r][2] = xv.z + qv.z; y[r][3] = xv.w + qv.w;
    s[r]  = (y[r][0] + y[r][1]) + (y[r][2] + y[r][3]);
    ss[r] = (y[r][0]*y[r][0] + y[r][1]*y[r][1]) + (y[r][2]*y[r][2] + y[r][3]*y[r][3]);
  }
#pragma unroll
  for (int off = 1; off < 64; off <<= 1) {
    s[0]  += __shfl_xor(s[0], off);  ss[0] += __shfl_xor(ss[0], off);
    s[1]  += __shfl_xor(s[1], off);  ss[1] += __shfl_xor(ss[1], off);
  }
  __shared__ float wsum[2][2][4];  // [r][{s,ss}][wave]
  const int wid = t >> 6;
  if ((t & 63) == 0) {
    wsum[0][0][wid] = s[0]; wsum[0][1][wid] = ss[0];
    wsum[1][0][wid] = s[1]; wsum[1][1][wid] = ss[1];
  }
  __syncthreads();
#pragma unroll
  for (int r = 0; r < 2; ++r) {
    float sr  = (wsum[r][0][0] + wsum[r][0][1]) + (wsum[r][0][2] + wsum[r][0][3]);
    float ssr = (wsum[r][1][0] + wsum[r][1][1]) + (wsum[r][1][2] + wsum[r][1][3]);
    const float mu   = sr * (1.f / NV);
    const float var  = ssr * (1.f / NV) - mu * mu;
    const float rstd = rsqrtf(var + LN_EPS);
    float4 o;
    o.x = gv.x * (y[r][0] - mu) * rstd + bv.x;
    o.y = gv.y * (y[r][1] - mu) * rstd + bv.y;
    o.z = gv.z * (y[r][2] - mu) * rstd + bv.z;
    o.w = gv.w * (y[r][3] - mu) * rstd + bv.w;
    *(float4*)(out + (size_t)(row0 + r) * NV + t * 4) = o;
  }
}

// ---------------------------------------------------------------------------
extern "C" void kernel_launch(void* const* d_in, const int* in_sizes, int n_in,
                              void* d_out, int out_size, void* d_ws, size_t ws_size,
                              hipStream_t stream) {
  const float* query = (const float*)d_in[0];
  const float* key_t = (const float*)d_in[1];
  const float* value = (const float*)d_in[2];
  const float* Wq    = (const float*)d_in[3];
  const float* Wk    = (const float*)d_in[4];
  const float* Wv    = (const float*)d_in[5];
  const float* gamma = (const float*)d_in[6];
  const float* beta  = (const float*)d_in[7];
  const int*   qmask = (const int*)d_in[8];
  const int*   vmask = (const int*)d_in[9];
  float* out = (float*)d_out;

  const size_t per = (size_t)NB * NH * SL * DH;  // 4,194,304 elements
  bf16_t* Qws = (bf16_t*)d_ws;
  bf16_t* Kws = Qws + per;
  bf16_t* Vws = Kws + per;   // transposed [bh][d][m], vm-masked
  bf16_t* Wtb = Vws + per;   // 3 * 1024*1024 bf16 = 6 MB
  bf16_t* Aq  = Wtb + (size_t)3 * NV * NV;  // bf16 casts of query/key/value
  bf16_t* Ak  = Aq + per;
  bf16_t* Av  = Ak + per;

  acvt<<<dim3((NB * SL * NV) / (256 * 4), 3), 256, 0, stream>>>(
      query, key_t, value, Aq, Ak, Av);
  wcvt<<<dim3(16, 16, 3), 256, 0, stream>>>(Wq, Wk, Wv, Wtb);
  proj_mfma<<<dim3(32, 8, 3), 256, 0, stream>>>(Aq, Ak, Av, Wtb,
                                                vmask, Qws, Kws, Vws);
  attn_mfma<<<512, 256, 0, stream>>>(Qws, Kws, Vws, qmask, out);
  ln_kernel<<<NB * SL / 2, 256, 0, stream>>>(out, query, gamma, beta, out);
}

// Round 13
// 206.216 us; speedup vs baseline: 1.1374x; 1.0157x over previous
//
#include <hip/hip_runtime.h>
#include <math.h>

constexpr int NB = 2;      // batch
constexpr int SL = 2048;   // sequence length
constexpr int NV = 1024;   // model dim
constexpr int NH = 16;     // heads
constexpr int DH = 64;     // head dim
constexpr float LN_EPS = 1e-3f;

typedef __bf16 bf16_t;
typedef __bf16 v8bf __attribute__((ext_vector_type(8)));
typedef float  v4f  __attribute__((ext_vector_type(4)));

__device__ __forceinline__ unsigned pack_bf16(float a, float b) {
  unsigned short ua = __builtin_bit_cast(unsigned short, (bf16_t)a);
  unsigned short ub = __builtin_bit_cast(unsigned short, (bf16_t)b);
  return (unsigned)ua | ((unsigned)ub << 16);
}
// async global->LDS, 16B/lane; LDS dest = wave-uniform base + lane*16.
__device__ __forceinline__ void async_cp16(const void* g, void* l) {
  __builtin_amdgcn_global_load_lds(
      (const __attribute__((address_space(1))) unsigned int*)g,
      (__attribute__((address_space(3))) unsigned int*)l, 16, 0, 0);
}

// ---------------------------------------------------------------------------
// A cast: fp32 -> bf16, fully coalesced (one float4 -> uint2 per thread).
__global__ __launch_bounds__(256)
void acvt(const float* __restrict__ q, const float* __restrict__ k,
          const float* __restrict__ v, bf16_t* __restrict__ oq,
          bf16_t* __restrict__ ok, bf16_t* __restrict__ ov) {
  const int z = blockIdx.y;
  const float* src = z == 0 ? q : (z == 1 ? k : v);
  bf16_t*      dst = z == 0 ? oq : (z == 1 ? ok : ov);
  const size_t i = ((size_t)blockIdx.x * 256 + threadIdx.x) * 4;
  float4 f = *(const float4*)(src + i);
  uint2 u = {pack_bf16(f.x, f.y), pack_bf16(f.z, f.w)};
  *(uint2*)(dst + i) = u;
}

// ---------------------------------------------------------------------------
// W transpose+convert: W[h][v][d] fp32 -> Wt[z][n=h*64+d][v] bf16.
// Scale (1/8 * log2e) folded into Wq (softmax then uses exp2 directly).
__global__ __launch_bounds__(256)
void wcvt(const float* __restrict__ Wq, const float* __restrict__ Wk,
          const float* __restrict__ Wv, bf16_t* __restrict__ Wt) {
  __shared__ float ls[64][65];
  const int z = blockIdx.z;
  const float* W = z == 0 ? Wq : (z == 1 ? Wk : Wv);
  const float sc = z == 0 ? 0.125f * 1.44269504f : 1.0f;
  const int h = blockIdx.y, v0 = blockIdx.x * 64;
  const int t = threadIdx.x;
  const int rr = t >> 4, c4 = t & 15;
  const float* src = W + ((size_t)h * NV + v0) * DH;
#pragma unroll
  for (int it = 0; it < 4; ++it) {
    float4 f = *(const float4*)(src + (size_t)(rr + it * 16) * DH + c4 * 4);
    ls[rr + it * 16][c4 * 4 + 0] = f.x;
    ls[rr + it * 16][c4 * 4 + 1] = f.y;
    ls[rr + it * 16][c4 * 4 + 2] = f.z;
    ls[rr + it * 16][c4 * 4 + 3] = f.w;
  }
  __syncthreads();
  const int dd = t >> 2, vq = t & 3;
  bf16_t tmp[16];
#pragma unroll
  for (int i = 0; i < 16; ++i) tmp[i] = (bf16_t)(ls[vq * 16 + i][dd] * sc);
  bf16_t* dst = Wt + ((size_t)z * NV + h * 64 + dd) * NV + v0 + vq * 16;
  *(v8bf*)dst = *(v8bf*)&tmp[0];
  *(v8bf*)(dst + 8) = *(v8bf*)&tmp[8];
}

// ---------------------------------------------------------------------------
// Projection GEMM, ALL-bf16 (A pre-cast by acvt). BK=32, double-buffered,
// ONE barrier/iter, 32KB LDS. Both operands DMA-staged as 64B rows (16 rows
// per async_cp16, fully coalesced), 4-chunk XOR swizzle.
// Q/K outputs [bh][l][d]; V output TRANSPOSED [bh][d][m], vm folded in.
__global__ __launch_bounds__(256, 4)
void proj_mfma(const bf16_t* __restrict__ A0, const bf16_t* __restrict__ A1,
               const bf16_t* __restrict__ A2, const bf16_t* __restrict__ Wtb,
               const int* __restrict__ vmask,
               bf16_t* __restrict__ O0, bf16_t* __restrict__ O1,
               bf16_t* __restrict__ O2) {
  __shared__ __align__(16) bf16_t Asb[2][128 * 32];  // [m][k] 64B rows, XOR swz
  __shared__ __align__(16) bf16_t Wsb[2][128 * 32];  // [n][k] 64B rows, XOR swz

  const int z = blockIdx.z;
  const bf16_t* A   = z == 0 ? A0 : (z == 1 ? A1 : A2);
  bf16_t*       out = z == 0 ? O0 : (z == 1 ? O1 : O2);
  const bf16_t* W   = Wtb + (size_t)z * NV * NV;

  const int t = threadIdx.x, w = t >> 6, lane = t & 63;
  const int g = lane >> 4, lx = lane & 15;
  const int m0 = blockIdx.x * 128, n0 = blockIdx.y * 128;
  const int rbase = (w >> 1) * 64, cbase = (w & 1) * 64;

  const int sr = lane >> 2;           // 16 rows per instr, 4 lanes/row
  const int sc = (lane & 3);
  auto stageA = [&](int k0, int buf) {
#pragma unroll
    for (int s = 0; s < 2; ++s) {
      const int r = w * 32 + s * 16 + sr;
      const int c = sc ^ (r & 3);
      async_cp16(A + (size_t)(m0 + r) * NV + k0 + c * 8,
                 (char*)Asb[buf] + (w * 32 + s * 16) * 64);
    }
  };
  auto stageW = [&](int k0, int buf) {
#pragma unroll
    for (int s = 0; s < 2; ++s) {
      const int r = w * 32 + s * 16 + sr;
      const int c = sc ^ (r & 3);
      async_cp16(W + (size_t)(n0 + r) * NV + k0 + c * 8,
                 (char*)Wsb[buf] + (w * 32 + s * 16) * 64);
    }
  };

  v4f acc[4][4] = {};
  stageA(0, 0);
  stageW(0, 0);

  for (int it = 0; it < 32; ++it) {
    const int buf = it & 1;
    __syncthreads();  // drains this iter's async; orders prev reads vs restage
    if (it < 31) {
      stageA((it + 1) * 32, buf ^ 1);
      stageW((it + 1) * 32, buf ^ 1);
    }
    v8bf af[4], wf[4];
#pragma unroll
    for (int rt = 0; rt < 4; ++rt) {
      const int row = rbase + rt * 16 + lx;
      af[rt] = *(const v8bf*)((const char*)Asb[buf] + row * 64 +
                              ((g ^ (row & 3)) * 16));
    }
#pragma unroll
    for (int ct = 0; ct < 4; ++ct) {
      const int row = cbase + ct * 16 + lx;
      wf[ct] = *(const v8bf*)((const char*)Wsb[buf] + row * 64 +
                              ((g ^ (row & 3)) * 16));
    }
#pragma unroll
    for (int rt = 0; rt < 4; ++rt)
#pragma unroll
      for (int ct = 0; ct < 4; ++ct)
        acc[rt][ct] = __builtin_amdgcn_mfma_f32_16x16x32_bf16(
            af[rt], wf[ct], acc[rt][ct], 0, 0, 0);
  }

  // epilogue. C-layout: row=(lane>>4)*4+reg, col=lane&15.
  if (z < 2) {  // Q/K: [bh][l][d]
#pragma unroll
    for (int rt = 0; rt < 4; ++rt) {
#pragma unroll
      for (int reg = 0; reg < 4; ++reg) {
        const int row = m0 + rbase + rt * 16 + g * 4 + reg;
        const int b = row >> 11, l = row & (SL - 1);
#pragma unroll
        for (int ct = 0; ct < 4; ++ct) {
          const int n = n0 + cbase + ct * 16 + lx;
          const int h = n >> 6, d = n & 63;
          out[((size_t)(b * NH + h) * SL + l) * DH + d] = (bf16_t)acc[rt][ct][reg];
        }
      }
    }
  } else {  // V: transposed [bh][d][m], vm folded in; b64 stores along m
#pragma unroll
    for (int rt = 0; rt < 4; ++rt) {
      const int row = m0 + rbase + rt * 16 + g * 4;  // regs = 4 consecutive m
      const int b = row >> 11, l = row & (SL - 1);
      float vm0 = (float)vmask[b * SL + l + 0];
      float vm1 = (float)vmask[b * SL + l + 1];
      float vm2 = (float)vmask[b * SL + l + 2];
      float vm3 = (float)vmask[b * SL + l + 3];
#pragma unroll
      for (int ct = 0; ct < 4; ++ct) {
        const int n = n0 + cbase + ct * 16 + lx;
        const int h = n >> 6, d = n & 63;
        uint2 u = {pack_bf16(acc[rt][ct][0] * vm0, acc[rt][ct][1] * vm1),
                   pack_bf16(acc[rt][ct][2] * vm2, acc[rt][ct][3] * vm3)};
        *(uint2*)&out[((size_t)(b * NH + h) * DH + d) * SL + l] = u;
      }
    }
  }
}

// ---------------------------------------------------------------------------
// Fused attention (r12 structure + anti-correlated CU pairing). q-tile 128,
// pure q-split (each wave: 32 q-rows x all m). Softmax denominator over ALL m
// (unmasked); PV masked by tril (vm folded into V^T); qm at epilogue. exp2,
// no max-tracking. K and V^T double-buffered via global_load_lds, one barrier
// per 64-m tile; P round-trip via wave-private LDS; wave-private epilogue.
// XCD swizzle. Pairing: ids 0..255 map qb=15..0 (heavy-first), ids 256..511
// map the COMPLEMENT qb=0..15, so under round-robin dispatch each CU's two
// resident blocks sum to uniform work (fixes the 14%-occupancy tail).
// Grid 512 (1D).
__global__ __launch_bounds__(256, 3)
void attn_mfma(const bf16_t* __restrict__ Qg, const bf16_t* __restrict__ Kg,
               const bf16_t* __restrict__ Vtg_all, const int* __restrict__ qmask,
               float* __restrict__ Xout) {
  __shared__ __align__(16) bf16_t kbuf[2][64 * 64];  // K[m][d], XOR swz
  __shared__ __align__(16) bf16_t vbuf[2][64 * 64];  // V^T[d][m], XOR swz
  __shared__ __align__(16) bf16_t Ps[4][32][72];     // per-wave P^T [q][m]

  const int id = blockIdx.x;
  const int bh = (id & 7) | ((id >> 7) << 3);  // same-XCD for fixed bh
  const int qraw = (id >> 3) & 15;
  const int qb = ((id >> 8) & 1) ? qraw : 15 - qraw;  // complement pairing
  const int t = threadIdx.x, w = t >> 6, lane = t & 63;
  const int g = lane >> 4, lx = lane & 15;
  const int b = bh >> 4, h = bh & 15;
  const int l0 = qb * 128;
  const int lastAct = 2 * qb + 1;              // last m-tile with causal overlap

  const bf16_t* Kb  = Kg + (size_t)bh * SL * DH;
  const bf16_t* Vtg = Vtg_all + (size_t)bh * DH * SL;  // [d][m]

  // persistent Q B-frags: wave covers q in [l0 + w*32, +32)
  v8bf qf[2][2];
#pragma unroll
  for (int qt = 0; qt < 2; ++qt)
#pragma unroll
    for (int ks = 0; ks < 2; ++ks)
      qf[qt][ks] = *(const v8bf*)&Qg[((size_t)bh * SL + l0 + w * 32 + qt * 16 + lx) * DH +
                                     ks * 32 + g * 8];

  v4f O[2][4] = {};          // [qt][dt]
  float suml[2] = {0.f, 0.f};

  const int sr_off = lane >> 3, sc_l = lane & 7;
  auto stageK = [&](int mb, int buf) {
#pragma unroll
    for (int s = 0; s < 2; ++s) {
      const int r = w * 16 + s * 8 + sr_off;
      const int c = sc_l ^ (r & 7);
      async_cp16(Kb + (size_t)(mb + r) * DH + c * 8,
                 (char*)kbuf[buf] + (w * 16 + s * 8) * 128);
    }
  };
  auto stageV = [&](int mb, int buf) {
#pragma unroll
    for (int s = 0; s < 2; ++s) {
      const int r = w * 16 + s * 8 + sr_off;  // r = d row
      const int c = sc_l ^ (r & 7);
      async_cp16(Vtg + (size_t)r * SL + mb + c * 8,
                 (char*)vbuf[buf] + (w * 16 + s * 8) * 128);
    }
  };

  stageK(0, 0);
  stageV(0, 0);

  // ---- active tiles (causal overlap with [l0, l0+128)): S, P, PV ----
  for (int mt = 0; mt <= lastAct; ++mt) {
    const int pb = mt & 1;
    __syncthreads();  // drains async for tile mt; orders prev reads vs restage
    if (mt < SL / 64 - 1)  stageK((mt + 1) * 64, pb ^ 1);
    if (mt + 1 <= lastAct) stageV((mt + 1) * 64, pb ^ 1);

    // S^T: rows = m (mt2*16 + g*4 + reg), cols = q (lx)
    v4f S[4][2];  // [mt2][qt]
#pragma unroll
    for (int mt2 = 0; mt2 < 4; ++mt2) {
      S[mt2][0] = (v4f){0.f, 0.f, 0.f, 0.f};
      S[mt2][1] = (v4f){0.f, 0.f, 0.f, 0.f};
    }
#pragma unroll
    for (int ks = 0; ks < 2; ++ks)
#pragma unroll
      for (int mt2 = 0; mt2 < 4; ++mt2) {
        const int row = mt2 * 16 + lx;
        v8bf kf = *(const v8bf*)((const char*)kbuf[pb] + row * 128 +
                                 (((ks * 4 + g) ^ (lx & 7)) * 16));
#pragma unroll
        for (int qt = 0; qt < 2; ++qt)
          S[mt2][qt] = __builtin_amdgcn_mfma_f32_16x16x32_bf16(
              kf, qf[qt][ks], S[mt2][qt], 0, 0, 0);
      }

    const bool diagzone = (mt >= 2 * qb);  // only straddling tiles need masks
#pragma unroll
    for (int mt2 = 0; mt2 < 4; ++mt2)
#pragma unroll
      for (int qt = 0; qt < 2; ++qt) {
        float e0 = __builtin_amdgcn_exp2f(S[mt2][qt][0]);
        float e1 = __builtin_amdgcn_exp2f(S[mt2][qt][1]);
        float e2 = __builtin_amdgcn_exp2f(S[mt2][qt][2]);
        float e3 = __builtin_amdgcn_exp2f(S[mt2][qt][3]);
        suml[qt] += (e0 + e1) + (e2 + e3);  // denominator: unmasked
        if (diagzone) {
          const int ml = mt * 64 + mt2 * 16 + g * 4;
          const int ql = l0 + w * 32 + qt * 16 + lx;
          e0 = (ml + 0 <= ql) ? e0 : 0.f;
          e1 = (ml + 1 <= ql) ? e1 : 0.f;
          e2 = (ml + 2 <= ql) ? e2 : 0.f;
          e3 = (ml + 3 <= ql) ? e3 : 0.f;
        }
        uint2 u = {pack_bf16(e0, e1), pack_bf16(e2, e3)};
        *(uint2*)&Ps[w][qt * 16 + lx][mt2 * 16 + g * 4] = u;
      }

    // O += P . V   (Ps wave-private: same-wave LDS ordering suffices)
#pragma unroll
    for (int ks = 0; ks < 2; ++ks) {
      v8bf pf[2];
#pragma unroll
      for (int qt = 0; qt < 2; ++qt)
        pf[qt] = *(const v8bf*)&Ps[w][qt * 16 + lx][ks * 32 + g * 8];
#pragma unroll
      for (int dt = 0; dt < 4; ++dt) {
        const int row = dt * 16 + lx;
        v8bf vf = *(const v8bf*)((const char*)vbuf[pb] + row * 128 +
                                 (((ks * 4 + g) ^ (lx & 7)) * 16));
#pragma unroll
        for (int qt = 0; qt < 2; ++qt)
          O[qt][dt] = __builtin_amdgcn_mfma_f32_16x16x32_bf16(
              pf[qt], vf, O[qt][dt], 0, 0, 0);
      }
    }
  }

  // ---- future tiles: denominator only ----
  for (int mt = lastAct + 1; mt < SL / 64; ++mt) {
    const int pb = mt & 1;
    __syncthreads();
    if (mt < SL / 64 - 1) stageK((mt + 1) * 64, pb ^ 1);
    v4f S[4][2];
#pragma unroll
    for (int mt2 = 0; mt2 < 4; ++mt2) {
      S[mt2][0] = (v4f){0.f, 0.f, 0.f, 0.f};
      S[mt2][1] = (v4f){0.f, 0.f, 0.f, 0.f};
    }
#pragma unroll
    for (int ks = 0; ks < 2; ++ks)
#pragma unroll
      for (int mt2 = 0; mt2 < 4; ++mt2) {
        const int row = mt2 * 16 + lx;
        v8bf kf = *(const v8bf*)((const char*)kbuf[pb] + row * 128 +
                                 (((ks * 4 + g) ^ (lx & 7)) * 16));
#pragma unroll
        for (int qt = 0; qt < 2; ++qt)
          S[mt2][qt] = __builtin_amdgcn_mfma_f32_16x16x32_bf16(
              kf, qf[qt][ks], S[mt2][qt], 0, 0, 0);
      }
#pragma unroll
    for (int mt2 = 0; mt2 < 4; ++mt2)
#pragma unroll
      for (int qt = 0; qt < 2; ++qt)
        suml[qt] += (__builtin_amdgcn_exp2f(S[mt2][qt][0]) +
                     __builtin_amdgcn_exp2f(S[mt2][qt][1])) +
                    (__builtin_amdgcn_exp2f(S[mt2][qt][2]) +
                     __builtin_amdgcn_exp2f(S[mt2][qt][3]));
  }

  // ---- wave-private epilogue (no barrier, no cross-wave traffic) ----
  suml[0] += __shfl_xor(suml[0], 16); suml[0] += __shfl_xor(suml[0], 32);
  suml[1] += __shfl_xor(suml[1], 16); suml[1] += __shfl_xor(suml[1], 32);
#pragma unroll
  for (int qt = 0; qt < 2; ++qt) {
#pragma unroll
    for (int reg = 0; reg < 4; ++reg) {
      const int q = l0 + w * 32 + qt * 16 + g * 4 + reg;
      const float den = __shfl(suml[qt], g * 4 + reg);
      const float inv = (float)qmask[b * SL + q] / den;
#pragma unroll
      for (int dt = 0; dt < 4; ++dt)
        Xout[((size_t)(b * SL + q)) * NV + h * DH + dt * 16 + lx] =
            O[qt][dt][reg] * inv;
    }
  }
}

// ---------------------------------------------------------------------------
// Residual + LayerNorm over last dim (V=1024). Wave-per-row, zero barriers:
// 4 rows/block, lane owns columns lane*4 + i*256 (each load instr perfectly
// coalesced), full reduction via shfl_xor butterfly.
__global__ __launch_bounds__(256)
void ln_kernel(const float* __restrict__ X, const float* __restrict__ query,
               const float* __restrict__ gamma, const float* __restrict__ beta,
               float* __restrict__ out) {
  const int row = blockIdx.x * 4 + (threadIdx.x >> 6);
  const int lane = threadIdx.x & 63;
  const float* xr = X + (size_t)row * NV;
  const float* qr = query + (size_t)row * NV;
  float4 y[4];
  float s = 0.f, ss = 0.f;
#pragma unroll
  for (int i = 0; i < 4; ++i) {
    const int col = lane * 4 + i * 256;
    float4 xv = *(const float4*)(xr + col);
    float4 qv = *(const float4*)(qr + col);
    y[i].x = xv.x + qv.x; y[i].y = xv.y + qv.y;
    y[i].z = xv.z + qv.z; y[i].w = xv.w + qv.w;
    s  += (y[i].x + y[i].y) + (y[i].z + y[i].w);
    ss += (y[i].x * y[i].x + y[i].y * y[i].y) +
          (y[i].z * y[i].z + y[i].w * y[i].w);
  }
#pragma unroll
  for (int off = 1; off < 64; off <<= 1) {
    s  += __shfl_xor(s, off);
    ss += __shfl_xor(ss, off);
  }
  const float mu   = s * (1.f / NV);
  const float var  = ss * (1.f / NV) - mu * mu;
  const float rstd = rsqrtf(var + LN_EPS);
#pragma unroll
  for (int i = 0; i < 4; ++i) {
    const int col = lane * 4 + i * 256;
    float4 gv = *(const float4*)(gamma + col);
    float4 bv = *(const float4*)(beta + col);
    float4 o;
    o.x = gv.x * (y[i].x - mu) * rstd + bv.x;
    o.y = gv.y * (y[i].y - mu) * rstd + bv.y;
    o.z = gv.z * (y[i].z - mu) * rstd + bv.z;
    o.w = gv.w * (y[i].w - mu) * rstd + bv.w;
    *(float4*)(out + (size_t)row * NV + col) = o;
  }
}

// ---------------------------------------------------------------------------
extern "C" void kernel_launch(void* const* d_in, const int* in_sizes, int n_in,
                              void* d_out, int out_size, void* d_ws, size_t ws_size,
                              hipStream_t stream) {
  const float* query = (const float*)d_in[0];
  const float* key_t = (const float*)d_in[1];
  const float* value = (const float*)d_in[2];
  const float* Wq    = (const float*)d_in[3];
  const float* Wk    = (const float*)d_in[4];
  const float* Wv    = (const float*)d_in[5];
  const float* gamma = (const float*)d_in[6];
  const float* beta  = (const float*)d_in[7];
  const int*   qmask = (const int*)d_in[8];
  const int*   vmask = (const int*)d_in[9];
  float* out = (float*)d_out;

  const size_t per = (size_t)NB * NH * SL * DH;  // 4,194,304 elements
  bf16_t* Qws = (bf16_t*)d_ws;
  bf16_t* Kws = Qws + per;
  bf16_t* Vws = Kws + per;   // transposed [bh][d][m], vm-masked
  bf16_t* Wtb = Vws + per;   // 3 * 1024*1024 bf16 = 6 MB
  bf16_t* Aq  = Wtb + (size_t)3 * NV * NV;  // bf16 casts of query/key/value
  bf16_t* Ak  = Aq + per;
  bf16_t* Av  = Ak + per;

  acvt<<<dim3((NB * SL * NV) / (256 * 4), 3), 256, 0, stream>>>(
      query, key_t, value, Aq, Ak, Av);
  wcvt<<<dim3(16, 16, 3), 256, 0, stream>>>(Wq, Wk, Wv, Wtb);
  proj_mfma<<<dim3(32, 8, 3), 256, 0, stream>>>(Aq, Ak, Av, Wtb,
                                                vmask, Qws, Kws, Vws);
  attn_mfma<<<512, 256, 0, stream>>>(Qws, Kws, Vws, qmask, out);
  ln_kernel<<<NB * SL / 4, 256, 0, stream>>>(out, query, gamma, beta, out);
}